// Round 9
// baseline (310.679 us; speedup 1.0000x reference)
//
#include <hip/hip_runtime.h>
#include <math.h>

#define BB 16
#define NCC 64
#define NN 256
#define DD 64

typedef short s16x8 __attribute__((ext_vector_type(8)));
typedef float f32x4 __attribute__((ext_vector_type(4)));

#define MFMA16(a,b,c) __builtin_amdgcn_mfma_f32_16x16x32_bf16((a),(b),(c),0,0,0)

__device__ __forceinline__ unsigned short f2bf(float f){
    union{float f;unsigned u;}v; v.f=f;
    unsigned r = v.u + 0x7FFFu + ((v.u>>16)&1u);   // RNE
    return (unsigned short)(r>>16);
}
__device__ __forceinline__ float bf2f(unsigned short s){
    union{unsigned u;float f;}v; v.u=((unsigned)s)<<16; return v.f;
}
// v_cvt_pk_bf16_f32: no builtin on gfx950 -> inline asm (T12 recipe)
__device__ __forceinline__ unsigned cvt2(float a,float b){
    unsigned r;
    asm("v_cvt_pk_bf16_f32 %0, %1, %2" : "=v"(r) : "v"(a), "v"(b));
    return r;
}
__device__ __forceinline__ unsigned short cvt1(float a){   // 1-op f32->bf16 RNE
    unsigned r;
    asm("v_cvt_pk_bf16_f32 %0, %1, %2" : "=v"(r) : "v"(a), "v"(a));
    return (unsigned short)r;
}
__device__ __forceinline__ s16x8 pack8(float4 lo,float4 hi){
    union{unsigned u[4];s16x8 v;}r;
    r.u[0]=cvt2(lo.x,lo.y); r.u[1]=cvt2(lo.z,lo.w);
    r.u[2]=cvt2(hi.x,hi.y); r.u[3]=cvt2(hi.z,hi.w);
    return r.v;
}
// tanh = 1 - 2/(exp2(x*2/ln2)+1): saturates correctly at +-inf, no clamp needed
__device__ __forceinline__ float tanh2(float x){
    float e = __builtin_amdgcn_exp2f(x * 2.8853900817779268f);
    return 1.0f - 2.0f * __builtin_amdgcn_rcpf(e + 1.0f);
}
__device__ __forceinline__ float sigm(float v){ return __builtin_amdgcn_rcpf(1.0f+__expf(-v)); }

// ---------------- weight f32 -> bf16 prep ----------------
extern "C" __global__ void __launch_bounds__(256)
wconv(const float* __restrict__ sw1, const float* __restrict__ sw2,
      const float* __restrict__ mw1, const float* __restrict__ mw2,
      unsigned short* __restrict__ ws)
{
    const int i = blockIdx.x * 256 + threadIdx.x;
    float v;
    if (i < 32768)      v = sw1[i];
    else if (i < 49152) v = sw2[i - 32768];
    else if (i < 65536) v = mw1[i - 49152];
    else                v = mw2[i - 65536];
    ws[i] = f2bf(v);
}

// ---------------- Kernel A: recv = W@msg (+ mod MLP, inject, border edits) ----------------
// ROUND-6 PROVEN STRUCTURE (passed rounds 4 & 6): one block per (b,c), 512 threads,
// W double-buffer via global_load_lds, stage rc+1 at iter start, vmcnt(4)/vmcnt(0).
extern "C" __global__ void __launch_bounds__(512,2)
mg_recv(const float* __restrict__ x, const float* __restrict__ msg,
        const float* __restrict__ W, const float* __restrict__ decay_logit,
        const float* __restrict__ cell_context, const float* __restrict__ border_gate_logit,
        const float* __restrict__ inject_w, const float* __restrict__ inject_b,
        const float* __restrict__ mod_w1, const float* __restrict__ mod_b1,
        const float* __restrict__ mod_w2, const float* __restrict__ mod_b2,
        const int* __restrict__ cell_to_group,
        unsigned short* __restrict__ ws_recv, float* __restrict__ ws_decay)
{
    __shared__ __align__(16) float s_w[2][32*260];            // 66560 B, pitch 260 f32
    __shared__ __align__(16) unsigned short s_msgT[64*264];   // 33792 B
    __shared__ float s_x[64], s_cc[64], s_hmod[64], s_mod[8], s_bgate[4];
    __shared__ float s_inj[256], s_bord[256];

    const int tid  = threadIdx.x;
    const int lane = tid & 63;
    const int l15  = lane & 15;
    const int g    = lane >> 4;
    const int wid  = __builtin_amdgcn_readfirstlane(tid >> 6);
    const int bc   = blockIdx.x;
    const int b    = bc >> 6;
    const int c    = bc & 63;
    const float* Wb = W + (size_t)bc * NN * NN;

#define STAGE_CHUNK(n) do{                                                            \
    const int _buf=(n)&1;                                                             \
    _Pragma("unroll")                                                                 \
    for(int _j=0;_j<4;++_j){                                                          \
        const int _row=4*wid+_j;                                                      \
        const float* _gp = Wb + (size_t)(32*(n)+_row)*NN + lane*4;                    \
        __builtin_amdgcn_global_load_lds(                                             \
            (const __attribute__((address_space(1))) void*)_gp,                       \
            (__attribute__((address_space(3))) void*)&s_w[_buf][_row*260], 16, 0, 0); \
    }                                                                                 \
}while(0)

    // deep-queue prefetch of W chunks 0 and 1 (8 x 1KB wave-loads in flight)
    STAGE_CHUNK(0);
    STAGE_CHUNK(1);

    // msg -> LDS transposed bf16 (msgT[d][m], pitch 264) -- overlaps W flight
    for (int it = tid; it < 2048; it += 512) {
        const int d4 = it & 15, mp = it >> 4;
        const float* src = msg + ((size_t)bc * NN + mp * 2) * DD + d4 * 4;
        const float4 v0 = *(const float4*)(src);
        const float4 v1 = *(const float4*)(src + DD);
        const float* p0 = &v0.x; const float* p1 = &v1.x;
        #pragma unroll
        for (int j = 0; j < 4; ++j)
            *(unsigned*)&s_msgT[(d4 * 4 + j) * 264 + mp * 2] = cvt2(p0[j], p1[j]);
    }

    asm volatile("s_waitcnt lgkmcnt(0)" ::: "memory");
    __builtin_amdgcn_sched_barrier(0);
    __builtin_amdgcn_s_barrier();          // msgT visible to all waves
    __builtin_amdgcn_sched_barrier(0);

    const int rt = wid & 1, ct = wid >> 1;
    for (int rc = 0; rc < 8; ++rc) {
        if (rc >= 1 && rc <= 6) STAGE_CHUNK(rc + 1);
        if (rc < 7) asm volatile("s_waitcnt vmcnt(4)" ::: "memory");
        else        asm volatile("s_waitcnt vmcnt(0)" ::: "memory");
        __builtin_amdgcn_sched_barrier(0);
        __builtin_amdgcn_s_barrier();      // chunk rc landed (all waves)
        __builtin_amdgcn_sched_barrier(0);
        {
            const float* wrow = &s_w[rc & 1][(16 * rt + l15) * 260];
            const unsigned short* brow = &s_msgT[(16 * ct + l15) * 264];
            f32x4 acc = {0.f, 0.f, 0.f, 0.f};
            #pragma unroll
            for (int k = 0; k < 8; ++k) {
                const float4 w0 = *(const float4*)(wrow + 32 * k + 8 * g);
                const float4 w1 = *(const float4*)(wrow + 32 * k + 8 * g + 4);
                const s16x8 bf = *(const s16x8*)(brow + 32 * k + 8 * g);
                acc = MFMA16(pack8(w0, w1), bf, acc);
            }
            const int rowb = 32 * rc + 16 * rt + 4 * g;
            unsigned short* op = ws_recv + ((size_t)bc * NN + rowb) * DD + 16 * ct + l15;
            #pragma unroll
            for (int i = 0; i < 4; ++i) op[i * DD] = cvt1(acc[i]);
        }
        __builtin_amdgcn_sched_barrier(0);
        __builtin_amdgcn_s_barrier();      // all waves done reading buf before re-stage
        __builtin_amdgcn_sched_barrier(0);
    }
#undef STAGE_CHUNK

    // ---- post-loop: mod MLP -> decay/bgate; inject; border; RMW edits ----
    if (tid < 64) {
        s_cc[tid] = cell_context[bc * DD + tid];
        s_x[tid]  = x[(size_t)b * (NCC * DD) + c * DD + tid];
    }
    __syncthreads();
    if (tid < 64) {
        float acc = mod_b1[c * 64 + tid];
        const float* wp = mod_w1 + (size_t)c * 64 * 64 + tid;
        #pragma unroll
        for (int d = 0; d < 64; ++d) acc += s_cc[d] * wp[d * 64];
        s_hmod[tid] = tanh2(acc);
    }
    __syncthreads();
    if (tid < 5) {
        float acc = mod_b2[c * 5 + tid];
        const float* wp = mod_w2 + (size_t)c * 64 * 5 + tid;
        #pragma unroll
        for (int hh = 0; hh < 64; ++hh) acc += s_hmod[hh] * wp[hh * 5];
        s_mod[tid] = acc;
    }
    __syncthreads();
    if (tid < 256) {
        ws_decay[bc * NN + tid] = sigm(decay_logit[(size_t)bc * NN + tid] + s_mod[0]);
        if (tid < 4) s_bgate[tid] = sigm(border_gate_logit[bc * 4 + tid] + s_mod[1 + tid]);
    }
    __syncthreads();
    if (tid < 256) {
        const int grp = cell_to_group[c];
        float acc = inject_b[grp * 256 + tid];
        const float4* wv = (const float4*)(inject_w + ((size_t)grp * 256 + tid) * 64);
        #pragma unroll
        for (int i4 = 0; i4 < 16; ++i4) {
            const float4 v = wv[i4];
            acc += v.x * s_x[i4 * 4 + 0] + v.y * s_x[i4 * 4 + 1]
                 + v.z * s_x[i4 * 4 + 2] + v.w * s_x[i4 * 4 + 3];
        }
        s_inj[tid] = acc;
    } else {
        const int q = tid - 256, p = q >> 6, d = q & 63;
        const int gi = c >> 3, gj = c & 7;
        int cn = -1, ps = 0;
        if (p == 0)      { if (gi > 0) { cn = c - 8; ps = 1; } }
        else if (p == 1) { if (gi < 7) { cn = c + 8; ps = 0; } }
        else if (p == 2) { if (gj > 0) { cn = c - 1; ps = 3; } }
        else             { if (gj < 7) { cn = c + 1; ps = 2; } }
        s_bord[q] = (cn >= 0) ? s_bgate[p] * msg[(((size_t)b * NCC + cn) * NN + 8 + ps) * DD + d]
                              : 0.0f;
    }
    __syncthreads();
    if (tid < 256) {                       // RMW edits rows 0..3 (inject), 8..11 (border)
        const int n = tid >> 6, d = tid & 63;
        unsigned short* base = ws_recv + (size_t)bc * NN * DD;
        unsigned short* p1 = base + n * DD + d;
        *p1 = f2bf(bf2f(*p1) + s_inj[tid]);
        unsigned short* p2 = base + (8 + n) * DD + d;
        *p2 = f2bf(bf2f(*p2) + s_bord[tid]);
    }
}

// ---------------- Kernel B: MLP chain per (b,c,tile-of-32) ----------------
// 8192 blocks x 256 threads, ~22.6 KB LDS, VGPR<=128 -> 16 waves/CU.
// Waves split by COLUMNS (64 in B/D, 16 in C/E); per-thread serial work halved.
extern "C" __global__ void __launch_bounds__(256,4)
mg_mlp(const float* __restrict__ h, const float* __restrict__ neuron_id,
       const float* __restrict__ state_b1, const float* __restrict__ state_b2,
       const float* __restrict__ msg_b1, const float* __restrict__ msg_b2,
       const unsigned short* __restrict__ sw1b, const unsigned short* __restrict__ sw2b,
       const unsigned short* __restrict__ mw1b, const unsigned short* __restrict__ mw2b,
       const unsigned short* __restrict__ ws_recv, const float* __restrict__ ws_decay,
       float* __restrict__ out_read, float* __restrict__ out_h, float* __restrict__ out_msg)
{
    __shared__ __align__(16) unsigned short s_hid[32*264];   // 16896 B
    __shared__ __align__(16) unsigned short s_h[32*72];      //  4608 B (h_new)
    __shared__ float s_mn[256];

    const int tid = threadIdx.x, lane = tid & 63, l15 = lane & 15, g = lane >> 4;
    const int wid = __builtin_amdgcn_readfirstlane(tid >> 6);
    const int bx = blockIdx.x, tile = bx & 7, bc = bx >> 3, b = bc >> 6, c = bc & 63;
    const int row0 = tile * 32;

    // ---- A-fragments (rt 0..1): recv bf16 direct; h f32 -> bf16 pack ----
    s16x8 ar0[2], ar1[2], ah0[2], ah1[2];
    #pragma unroll
    for (int rt = 0; rt < 2; ++rt) {
        const unsigned short* rrow = ws_recv + ((size_t)bc * NN + row0 + 16 * rt + l15) * DD;
        ar0[rt] = *(const s16x8*)(rrow + 8 * g);
        ar1[rt] = *(const s16x8*)(rrow + 32 + 8 * g);
        const float* hrow = h + ((size_t)bc * NN + row0 + 16 * rt + l15) * DD;
        ah0[rt] = pack8(*(const float4*)(hrow + 8 * g),      *(const float4*)(hrow + 8 * g + 4));
        ah1[rt] = pack8(*(const float4*)(hrow + 32 + 8 * g), *(const float4*)(hrow + 36 + 8 * g));
    }

    // ---- Phase B: hid_s = tanh([recv|h] @ sw1^T + b1), cols [64*wid, +64) ----
    #pragma unroll
    for (int cc = 0; cc < 4; ++cc) {
        const int n0 = 64 * wid + 16 * cc;
        const unsigned short* Bb = sw1b + (size_t)(n0 + l15) * 128;
        const s16x8 w0 = *(const s16x8*)(Bb + 8 * g);
        const s16x8 w1 = *(const s16x8*)(Bb + 32 + 8 * g);
        const s16x8 w2 = *(const s16x8*)(Bb + 64 + 8 * g);
        const s16x8 w3 = *(const s16x8*)(Bb + 96 + 8 * g);
        const float bias = state_b1[n0 + l15];
        #pragma unroll
        for (int rt = 0; rt < 2; ++rt) {
            f32x4 acc = {0.f, 0.f, 0.f, 0.f};
            acc = MFMA16(ar0[rt], w0, acc);
            acc = MFMA16(ar1[rt], w1, acc);
            acc = MFMA16(ah0[rt], w2, acc);
            acc = MFMA16(ah1[rt], w3, acc);
            #pragma unroll
            for (int i = 0; i < 4; ++i)
                s_hid[(16 * rt + 4 * g + i) * 264 + n0 + l15] = cvt1(tanh2(acc[i] + bias));
        }
    }
    __syncthreads();

    // ---- Phase C: cand + decay blend, cols [16*wid, +16) ----
    {
        const int d0 = 16 * wid + l15;
        const unsigned short* B0 = sw2b + (size_t)d0 * 256;
        s16x8 wf[8];
        #pragma unroll
        for (int k = 0; k < 8; ++k) wf[k] = *(const s16x8*)(B0 + 32 * k + 8 * g);
        const float sb = state_b2[d0];
        float hvv[8], dcc[8];
        #pragma unroll
        for (int rt = 0; rt < 2; ++rt)
            #pragma unroll
            for (int i = 0; i < 4; ++i) {
                const int grow = row0 + 16 * rt + 4 * g + i;
                hvv[rt * 4 + i] = h[((size_t)bc * NN + grow) * DD + d0];
                dcc[rt * 4 + i] = ws_decay[bc * NN + grow];
            }
        #pragma unroll
        for (int rt = 0; rt < 2; ++rt) {
            f32x4 acc = {0.f, 0.f, 0.f, 0.f};
            #pragma unroll
            for (int k = 0; k < 8; ++k) {
                const s16x8 af = *(const s16x8*)&s_hid[(16 * rt + l15) * 264 + 32 * k + 8 * g];
                acc = MFMA16(af, wf[k], acc);
            }
            #pragma unroll
            for (int i = 0; i < 4; ++i) {
                const int lrow = 16 * rt + 4 * g + i, grow = row0 + lrow;
                const float dec = dcc[rt * 4 + i];
                const float hn  = dec * hvv[rt * 4 + i] + (1.0f - dec) * tanh2(acc[i] + sb);
                s_h[lrow * 72 + d0] = cvt1(hn);
                out_h[((size_t)bc * NN + grow) * DD + d0] = hn;
            }
        }
    }
    __syncthreads();

    // ---- Phase D: hid_m = tanh(h_new @ mw1^T + b1m), cols [64*wid, +64) ----
    {
        s16x8 hn0[2], hn1[2];
        #pragma unroll
        for (int rt = 0; rt < 2; ++rt) {
            const int hr = (16 * rt + l15) * 72;
            hn0[rt] = *(const s16x8*)&s_h[hr + 8 * g];
            hn1[rt] = *(const s16x8*)&s_h[hr + 32 + 8 * g];
        }
        #pragma unroll
        for (int cc = 0; cc < 4; ++cc) {
            const int n0 = 64 * wid + 16 * cc;
            const unsigned short* Bb = mw1b + (size_t)(n0 + l15) * 64;
            const s16x8 w0 = *(const s16x8*)(Bb + 8 * g);
            const s16x8 w1 = *(const s16x8*)(Bb + 32 + 8 * g);
            const float bias = msg_b1[n0 + l15];
            #pragma unroll
            for (int rt = 0; rt < 2; ++rt) {
                f32x4 acc = {0.f, 0.f, 0.f, 0.f};
                acc = MFMA16(hn0[rt], w0, acc);
                acc = MFMA16(hn1[rt], w1, acc);
                #pragma unroll
                for (int i = 0; i < 4; ++i)
                    s_hid[(16 * rt + 4 * g + i) * 264 + n0 + l15] = cvt1(tanh2(acc[i] + bias));
            }
        }
    }
    __syncthreads();

    // ---- Phase E: msg_new = tanh(hid_m @ mw2^T + b2m) + neuron_id, cols [16*wid, +16) ----
    {
        const int d0 = 16 * wid + l15;
        const unsigned short* B0 = mw2b + (size_t)d0 * 256;
        s16x8 wf[8];
        #pragma unroll
        for (int k = 0; k < 8; ++k) wf[k] = *(const s16x8*)(B0 + 32 * k + 8 * g);
        const float mb = msg_b2[d0];
        float nid[8];
        #pragma unroll
        for (int rt = 0; rt < 2; ++rt)
            #pragma unroll
            for (int i = 0; i < 4; ++i)
                nid[rt * 4 + i] = neuron_id[((size_t)c * NN + row0 + 16 * rt + 4 * g + i) * DD + d0];
        #pragma unroll
        for (int rt = 0; rt < 2; ++rt) {
            f32x4 acc = {0.f, 0.f, 0.f, 0.f};
            #pragma unroll
            for (int k = 0; k < 8; ++k) {
                const s16x8 af = *(const s16x8*)&s_hid[(16 * rt + l15) * 264 + 32 * k + 8 * g];
                acc = MFMA16(af, wf[k], acc);
            }
            #pragma unroll
            for (int i = 0; i < 4; ++i) {
                const int lrow = 16 * rt + 4 * g + i, grow = row0 + lrow;
                const float m = tanh2(acc[i] + mb) + nid[rt * 4 + i];
                out_msg[((size_t)bc * NN + grow) * DD + d0] = m;
                if (tile == 0 && lrow >= 4 && lrow < 8) s_mn[(lrow - 4) * 64 + d0] = m;
            }
        }
    }
    __syncthreads();
    if (tile == 0 && tid < 64)
        out_read[(size_t)b * (NCC * DD) + c * 64 + tid] =
            0.25f * (s_mn[tid] + s_mn[64 + tid] + s_mn[128 + tid] + s_mn[192 + tid]);
}

extern "C" void kernel_launch(void* const* d_in, const int* in_sizes, int n_in,
                              void* d_out, int out_size, void* d_ws, size_t ws_size,
                              hipStream_t stream) {
    (void)in_sizes; (void)n_in; (void)ws_size; (void)out_size;
    const float* x                 = (const float*)d_in[0];
    const float* h                 = (const float*)d_in[1];
    const float* msg               = (const float*)d_in[2];
    const float* W                 = (const float*)d_in[3];
    const float* decay_logit       = (const float*)d_in[4];
    const float* cell_context      = (const float*)d_in[5];
    const float* border_gate_logit = (const float*)d_in[6];
    const float* neuron_id         = (const float*)d_in[7];
    const float* state_w1          = (const float*)d_in[8];
    const float* state_b1          = (const float*)d_in[9];
    const float* state_w2          = (const float*)d_in[10];
    const float* state_b2          = (const float*)d_in[11];
    const float* msg_w1            = (const float*)d_in[12];
    const float* msg_b1            = (const float*)d_in[13];
    const float* msg_w2            = (const float*)d_in[14];
    const float* msg_b2            = (const float*)d_in[15];
    const float* inject_w          = (const float*)d_in[16];
    const float* inject_b          = (const float*)d_in[17];
    const float* mod_w1            = (const float*)d_in[18];
    const float* mod_b1            = (const float*)d_in[19];
    const float* mod_w2            = (const float*)d_in[20];
    const float* mod_b2            = (const float*)d_in[21];
    const int*   cell_to_group     = (const int*)d_in[22];

    float* out_read = (float*)d_out;
    float* out_h    = out_read + (size_t)BB * NCC * DD;
    float* out_msg  = out_h + (size_t)BB * NCC * NN * DD;

    // ws layout (bytes): [0,163840) bf16 weights | [163840,1212416) decay f32
    //                    | [1212416,34766848) recv bf16
    unsigned short* ws16   = (unsigned short*)d_ws;
    unsigned short* sw1b   = ws16;
    unsigned short* sw2b   = ws16 + 32768;
    unsigned short* mw1b   = ws16 + 49152;
    unsigned short* mw2b   = ws16 + 65536;
    float*          ws_dec = (float*)((char*)d_ws + 163840);
    unsigned short* ws_rcv = (unsigned short*)((char*)d_ws + 1212416);

    hipLaunchKernelGGL(wconv, dim3(320), dim3(256), 0, stream,
                       state_w1, state_w2, msg_w1, msg_w2, ws16);

    hipLaunchKernelGGL(mg_recv, dim3(BB * NCC), dim3(512), 0, stream,
                       x, msg, W, decay_logit, cell_context, border_gate_logit,
                       inject_w, inject_b, mod_w1, mod_b1, mod_w2, mod_b2,
                       cell_to_group, ws_rcv, ws_dec);

    hipLaunchKernelGGL(mg_mlp, dim3(BB * NCC * 8), dim3(256), 0, stream,
                       h, neuron_id, state_b1, state_b2, msg_b1, msg_b2,
                       sw1b, sw2b, mw1b, mw2b, ws_rcv, ws_dec,
                       out_read, out_h, out_msg);
}

// Round 11
// 242.996 us; speedup vs baseline: 1.2785x; 1.2785x over previous
//
#include <hip/hip_runtime.h>
#include <math.h>

#define BB 16
#define NCC 64
#define NN 256
#define DD 64

typedef short s16x8 __attribute__((ext_vector_type(8)));
typedef float f32x4 __attribute__((ext_vector_type(4)));

#define MFMA16(a,b,c) __builtin_amdgcn_mfma_f32_16x16x32_bf16((a),(b),(c),0,0,0)

__device__ __forceinline__ unsigned short f2bf(float f){
    union{float f;unsigned u;}v; v.f=f;
    unsigned r = v.u + 0x7FFFu + ((v.u>>16)&1u);   // RNE
    return (unsigned short)(r>>16);
}
__device__ __forceinline__ float bf2f(unsigned short s){
    union{unsigned u;float f;}v; v.u=((unsigned)s)<<16; return v.f;
}
// v_cvt_pk_bf16_f32: no builtin on gfx950 -> inline asm (T12 recipe)
__device__ __forceinline__ unsigned cvt2(float a,float b){
    unsigned r;
    asm("v_cvt_pk_bf16_f32 %0, %1, %2" : "=v"(r) : "v"(a), "v"(b));
    return r;
}
__device__ __forceinline__ unsigned short cvt1(float a){   // 1-op f32->bf16 RNE
    unsigned r;
    asm("v_cvt_pk_bf16_f32 %0, %1, %2" : "=v"(r) : "v"(a), "v"(a));
    return (unsigned short)r;
}
__device__ __forceinline__ s16x8 pack8(float4 lo,float4 hi){
    union{unsigned u[4];s16x8 v;}r;
    r.u[0]=cvt2(lo.x,lo.y); r.u[1]=cvt2(lo.z,lo.w);
    r.u[2]=cvt2(hi.x,hi.y); r.u[3]=cvt2(hi.z,hi.w);
    return r.v;
}
// tanh = 1 - 2/(exp2(x*2/ln2)+1): saturates correctly at +-inf, no clamp needed
__device__ __forceinline__ float tanh2(float x){
    float e = __builtin_amdgcn_exp2f(x * 2.8853900817779268f);
    return 1.0f - 2.0f * __builtin_amdgcn_rcpf(e + 1.0f);
}
__device__ __forceinline__ float sigm(float v){ return __builtin_amdgcn_rcpf(1.0f+__expf(-v)); }

// ---------------- weight f32 -> bf16 prep ----------------
extern "C" __global__ void __launch_bounds__(256)
wconv(const float* __restrict__ sw1, const float* __restrict__ sw2,
      const float* __restrict__ mw1, const float* __restrict__ mw2,
      unsigned short* __restrict__ ws)
{
    const int i = blockIdx.x * 256 + threadIdx.x;
    float v;
    if (i < 32768)      v = sw1[i];
    else if (i < 49152) v = sw2[i - 32768];
    else if (i < 65536) v = mw1[i - 49152];
    else                v = mw2[i - 65536];
    ws[i] = f2bf(v);
}

// ---------------- Kernel A: recv = W@msg (+ mod MLP, inject, border edits) ----------------
// ROUND-6 PROVEN STRUCTURE, VERBATIM (passed rounds 4, 6, 9): one block per (b,c),
// 512 threads, W double-buffer via global_load_lds, stage rc+1 at iter start,
// vmcnt(4)/vmcnt(0).
extern "C" __global__ void __launch_bounds__(512,2)
mg_recv(const float* __restrict__ x, const float* __restrict__ msg,
        const float* __restrict__ W, const float* __restrict__ decay_logit,
        const float* __restrict__ cell_context, const float* __restrict__ border_gate_logit,
        const float* __restrict__ inject_w, const float* __restrict__ inject_b,
        const float* __restrict__ mod_w1, const float* __restrict__ mod_b1,
        const float* __restrict__ mod_w2, const float* __restrict__ mod_b2,
        const int* __restrict__ cell_to_group,
        unsigned short* __restrict__ ws_recv, float* __restrict__ ws_decay)
{
    __shared__ __align__(16) float s_w[2][32*260];            // 66560 B, pitch 260 f32
    __shared__ __align__(16) unsigned short s_msgT[64*264];   // 33792 B
    __shared__ float s_x[64], s_cc[64], s_hmod[64], s_mod[8], s_bgate[4];
    __shared__ float s_inj[256], s_bord[256];

    const int tid  = threadIdx.x;
    const int lane = tid & 63;
    const int l15  = lane & 15;
    const int g    = lane >> 4;
    const int wid  = __builtin_amdgcn_readfirstlane(tid >> 6);
    const int bc   = blockIdx.x;
    const int b    = bc >> 6;
    const int c    = bc & 63;
    const float* Wb = W + (size_t)bc * NN * NN;

#define STAGE_CHUNK(n) do{                                                            \
    const int _buf=(n)&1;                                                             \
    _Pragma("unroll")                                                                 \
    for(int _j=0;_j<4;++_j){                                                          \
        const int _row=4*wid+_j;                                                      \
        const float* _gp = Wb + (size_t)(32*(n)+_row)*NN + lane*4;                    \
        __builtin_amdgcn_global_load_lds(                                             \
            (const __attribute__((address_space(1))) void*)_gp,                       \
            (__attribute__((address_space(3))) void*)&s_w[_buf][_row*260], 16, 0, 0); \
    }                                                                                 \
}while(0)

    // deep-queue prefetch of W chunks 0 and 1 (8 x 1KB wave-loads in flight)
    STAGE_CHUNK(0);
    STAGE_CHUNK(1);

    // msg -> LDS transposed bf16 (msgT[d][m], pitch 264) -- overlaps W flight
    for (int it = tid; it < 2048; it += 512) {
        const int d4 = it & 15, mp = it >> 4;
        const float* src = msg + ((size_t)bc * NN + mp * 2) * DD + d4 * 4;
        const float4 v0 = *(const float4*)(src);
        const float4 v1 = *(const float4*)(src + DD);
        const float* p0 = &v0.x; const float* p1 = &v1.x;
        #pragma unroll
        for (int j = 0; j < 4; ++j)
            *(unsigned*)&s_msgT[(d4 * 4 + j) * 264 + mp * 2] = cvt2(p0[j], p1[j]);
    }

    asm volatile("s_waitcnt lgkmcnt(0)" ::: "memory");
    __builtin_amdgcn_sched_barrier(0);
    __builtin_amdgcn_s_barrier();          // msgT visible to all waves
    __builtin_amdgcn_sched_barrier(0);

    const int rt = wid & 1, ct = wid >> 1;
    for (int rc = 0; rc < 8; ++rc) {
        if (rc >= 1 && rc <= 6) STAGE_CHUNK(rc + 1);
        if (rc < 7) asm volatile("s_waitcnt vmcnt(4)" ::: "memory");
        else        asm volatile("s_waitcnt vmcnt(0)" ::: "memory");
        __builtin_amdgcn_sched_barrier(0);
        __builtin_amdgcn_s_barrier();      // chunk rc landed (all waves)
        __builtin_amdgcn_sched_barrier(0);
        {
            const float* wrow = &s_w[rc & 1][(16 * rt + l15) * 260];
            const unsigned short* brow = &s_msgT[(16 * ct + l15) * 264];
            f32x4 acc = {0.f, 0.f, 0.f, 0.f};
            #pragma unroll
            for (int k = 0; k < 8; ++k) {
                const float4 w0 = *(const float4*)(wrow + 32 * k + 8 * g);
                const float4 w1 = *(const float4*)(wrow + 32 * k + 8 * g + 4);
                const s16x8 bf = *(const s16x8*)(brow + 32 * k + 8 * g);
                acc = MFMA16(pack8(w0, w1), bf, acc);
            }
            const int rowb = 32 * rc + 16 * rt + 4 * g;
            unsigned short* op = ws_recv + ((size_t)bc * NN + rowb) * DD + 16 * ct + l15;
            #pragma unroll
            for (int i = 0; i < 4; ++i) op[i * DD] = cvt1(acc[i]);
        }
        __builtin_amdgcn_sched_barrier(0);
        __builtin_amdgcn_s_barrier();      // all waves done reading buf before re-stage
        __builtin_amdgcn_sched_barrier(0);
    }
#undef STAGE_CHUNK

    // ---- post-loop: mod MLP -> decay/bgate; inject; border; RMW edits ----
    if (tid < 64) {
        s_cc[tid] = cell_context[bc * DD + tid];
        s_x[tid]  = x[(size_t)b * (NCC * DD) + c * DD + tid];
    }
    __syncthreads();
    if (tid < 64) {
        float acc = mod_b1[c * 64 + tid];
        const float* wp = mod_w1 + (size_t)c * 64 * 64 + tid;
        #pragma unroll
        for (int d = 0; d < 64; ++d) acc += s_cc[d] * wp[d * 64];
        s_hmod[tid] = tanh2(acc);
    }
    __syncthreads();
    if (tid < 5) {
        float acc = mod_b2[c * 5 + tid];
        const float* wp = mod_w2 + (size_t)c * 64 * 5 + tid;
        #pragma unroll
        for (int hh = 0; hh < 64; ++hh) acc += s_hmod[hh] * wp[hh * 5];
        s_mod[tid] = acc;
    }
    __syncthreads();
    if (tid < 256) {
        ws_decay[bc * NN + tid] = sigm(decay_logit[(size_t)bc * NN + tid] + s_mod[0]);
        if (tid < 4) s_bgate[tid] = sigm(border_gate_logit[bc * 4 + tid] + s_mod[1 + tid]);
    }
    __syncthreads();
    if (tid < 256) {
        const int grp = cell_to_group[c];
        float acc = inject_b[grp * 256 + tid];
        const float4* wv = (const float4*)(inject_w + ((size_t)grp * 256 + tid) * 64);
        #pragma unroll
        for (int i4 = 0; i4 < 16; ++i4) {
            const float4 v = wv[i4];
            acc += v.x * s_x[i4 * 4 + 0] + v.y * s_x[i4 * 4 + 1]
                 + v.z * s_x[i4 * 4 + 2] + v.w * s_x[i4 * 4 + 3];
        }
        s_inj[tid] = acc;
    } else {
        const int q = tid - 256, p = q >> 6, d = q & 63;
        const int gi = c >> 3, gj = c & 7;
        int cn = -1, ps = 0;
        if (p == 0)      { if (gi > 0) { cn = c - 8; ps = 1; } }
        else if (p == 1) { if (gi < 7) { cn = c + 8; ps = 0; } }
        else if (p == 2) { if (gj > 0) { cn = c - 1; ps = 3; } }
        else             { if (gj < 7) { cn = c + 1; ps = 2; } }
        s_bord[q] = (cn >= 0) ? s_bgate[p] * msg[(((size_t)b * NCC + cn) * NN + 8 + ps) * DD + d]
                              : 0.0f;
    }
    __syncthreads();
    if (tid < 256) {                       // RMW edits rows 0..3 (inject), 8..11 (border)
        const int n = tid >> 6, d = tid & 63;
        unsigned short* base = ws_recv + (size_t)bc * NN * DD;
        unsigned short* p1 = base + n * DD + d;
        *p1 = f2bf(bf2f(*p1) + s_inj[tid]);
        unsigned short* p2 = base + (8 + n) * DD + d;
        *p2 = f2bf(bf2f(*p2) + s_bord[tid]);
    }
}

// ---------------- Kernel B: MLP chain per (b,c,tile-of-64) ----------------
// R6 body VERBATIM; ONLY change: __launch_bounds__(256,3) -> (256,2) so the
// batched weight fragments stay resident (r6/r9 VGPR=84/52 showed the caps
// forced rematerialization -> reload-bloated VALU). LDS 44KB still allows 2 blk/CU.
extern "C" __global__ void __launch_bounds__(256,2)
mg_mlp(const float* __restrict__ h, const float* __restrict__ neuron_id,
       const float* __restrict__ state_b1, const float* __restrict__ state_b2,
       const float* __restrict__ msg_b1, const float* __restrict__ msg_b2,
       const unsigned short* __restrict__ sw1b, const unsigned short* __restrict__ sw2b,
       const unsigned short* __restrict__ mw1b, const unsigned short* __restrict__ mw2b,
       const unsigned short* __restrict__ ws_recv, const float* __restrict__ ws_decay,
       float* __restrict__ out_read, float* __restrict__ out_h, float* __restrict__ out_msg)
{
    __shared__ __align__(16) unsigned short s_hid[64*264];   // 33792 B
    __shared__ __align__(16) unsigned short s_h[64*72];      //  9216 B (h_new)
    __shared__ float s_mn[256];

    const int tid = threadIdx.x, lane = tid & 63, l15 = lane & 15, g = lane >> 4;
    const int wid = __builtin_amdgcn_readfirstlane(tid >> 6);
    const int bx = blockIdx.x, tile = bx & 3, bc = bx >> 2, b = bc >> 6, c = bc & 63;
    const int row0 = tile * 64;

    // ---- batched loads: A-fragments + ALL phase-B weight fragments ----
    s16x8 ar0[4], ar1[4], ah0[4], ah1[4];
    #pragma unroll
    for (int rt = 0; rt < 4; ++rt) {
        const unsigned short* rrow = ws_recv + ((size_t)bc * NN + row0 + 16 * rt + l15) * DD;
        ar0[rt] = *(const s16x8*)(rrow + 8 * g);
        ar1[rt] = *(const s16x8*)(rrow + 32 + 8 * g);
        const float* hrow = h + ((size_t)bc * NN + row0 + 16 * rt + l15) * DD;
        ah0[rt] = pack8(*(const float4*)(hrow + 8 * g),      *(const float4*)(hrow + 8 * g + 4));
        ah1[rt] = pack8(*(const float4*)(hrow + 32 + 8 * g), *(const float4*)(hrow + 36 + 8 * g));
    }
    s16x8 wB[16];
    float biasB[4];
    #pragma unroll
    for (int cc = 0; cc < 4; ++cc) {
        const unsigned short* Bb = sw1b + (size_t)(64 * wid + 16 * cc + l15) * 128;
        wB[cc * 4 + 0] = *(const s16x8*)(Bb + 8 * g);
        wB[cc * 4 + 1] = *(const s16x8*)(Bb + 32 + 8 * g);
        wB[cc * 4 + 2] = *(const s16x8*)(Bb + 64 + 8 * g);
        wB[cc * 4 + 3] = *(const s16x8*)(Bb + 96 + 8 * g);
        biasB[cc] = state_b1[64 * wid + 16 * cc + l15];
    }

    // ---- Phase B: hid_s = tanh([recv|h] @ sw1^T + b1), cols [64*wid, +64) ----
    #pragma unroll
    for (int cc = 0; cc < 4; ++cc) {
        const int n0 = 64 * wid + 16 * cc;
        #pragma unroll
        for (int rt = 0; rt < 4; ++rt) {
            f32x4 acc = {0.f, 0.f, 0.f, 0.f};
            acc = MFMA16(ar0[rt], wB[cc * 4 + 0], acc);
            acc = MFMA16(ar1[rt], wB[cc * 4 + 1], acc);
            acc = MFMA16(ah0[rt], wB[cc * 4 + 2], acc);
            acc = MFMA16(ah1[rt], wB[cc * 4 + 3], acc);
            #pragma unroll
            for (int i = 0; i < 4; ++i)
                s_hid[(16 * rt + 4 * g + i) * 264 + n0 + l15] = cvt1(tanh2(acc[i] + biasB[cc]));
        }
    }
    __syncthreads();

    // ---- Phase C: cand + decay blend, cols [16*wid, +16) ----
    {
        const int d0 = 16 * wid + l15;
        const unsigned short* B0 = sw2b + (size_t)d0 * 256;
        s16x8 wf[8];
        #pragma unroll
        for (int k = 0; k < 8; ++k) wf[k] = *(const s16x8*)(B0 + 32 * k + 8 * g);
        const float sb = state_b2[d0];
        float hvv[16], dcc[16];
        #pragma unroll
        for (int rt = 0; rt < 4; ++rt)
            #pragma unroll
            for (int i = 0; i < 4; ++i) {
                const int grow = row0 + 16 * rt + 4 * g + i;
                hvv[rt * 4 + i] = h[((size_t)bc * NN + grow) * DD + d0];
                dcc[rt * 4 + i] = ws_decay[bc * NN + grow];
            }
        #pragma unroll
        for (int rt = 0; rt < 4; ++rt) {
            f32x4 acc = {0.f, 0.f, 0.f, 0.f};
            #pragma unroll
            for (int k = 0; k < 8; ++k) {
                const s16x8 af = *(const s16x8*)&s_hid[(16 * rt + l15) * 264 + 32 * k + 8 * g];
                acc = MFMA16(af, wf[k], acc);
            }
            #pragma unroll
            for (int i = 0; i < 4; ++i) {
                const int lrow = 16 * rt + 4 * g + i, grow = row0 + lrow;
                const float dec = dcc[rt * 4 + i];
                const float hn  = dec * hvv[rt * 4 + i] + (1.0f - dec) * tanh2(acc[i] + sb);
                s_h[lrow * 72 + d0] = cvt1(hn);
                out_h[((size_t)bc * NN + grow) * DD + d0] = hn;
            }
        }
    }
    __syncthreads();

    // ---- Phase D: hid_m = tanh(h_new @ mw1^T + b1m), cols [64*wid, +64) ----
    {
        s16x8 hn0[4], hn1[4];
        #pragma unroll
        for (int rt = 0; rt < 4; ++rt) {
            const int hr = (16 * rt + l15) * 72;
            hn0[rt] = *(const s16x8*)&s_h[hr + 8 * g];
            hn1[rt] = *(const s16x8*)&s_h[hr + 32 + 8 * g];
        }
        s16x8 wD[8];
        float biasD[4];
        #pragma unroll
        for (int cc = 0; cc < 4; ++cc) {
            const unsigned short* Bb = mw1b + (size_t)(64 * wid + 16 * cc + l15) * 64;
            wD[cc * 2 + 0] = *(const s16x8*)(Bb + 8 * g);
            wD[cc * 2 + 1] = *(const s16x8*)(Bb + 32 + 8 * g);
            biasD[cc] = msg_b1[64 * wid + 16 * cc + l15];
        }
        #pragma unroll
        for (int cc = 0; cc < 4; ++cc) {
            const int n0 = 64 * wid + 16 * cc;
            #pragma unroll
            for (int rt = 0; rt < 4; ++rt) {
                f32x4 acc = {0.f, 0.f, 0.f, 0.f};
                acc = MFMA16(hn0[rt], wD[cc * 2 + 0], acc);
                acc = MFMA16(hn1[rt], wD[cc * 2 + 1], acc);
                #pragma unroll
                for (int i = 0; i < 4; ++i)
                    s_hid[(16 * rt + 4 * g + i) * 264 + n0 + l15] = cvt1(tanh2(acc[i] + biasD[cc]));
            }
        }
    }
    __syncthreads();

    // ---- Phase E: msg_new = tanh(hid_m @ mw2^T + b2m) + neuron_id, cols [16*wid, +16) ----
    {
        const int d0 = 16 * wid + l15;
        const unsigned short* B0 = mw2b + (size_t)d0 * 256;
        s16x8 wf[8];
        #pragma unroll
        for (int k = 0; k < 8; ++k) wf[k] = *(const s16x8*)(B0 + 32 * k + 8 * g);
        const float mb = msg_b2[d0];
        float nid[16];
        #pragma unroll
        for (int rt = 0; rt < 4; ++rt)
            #pragma unroll
            for (int i = 0; i < 4; ++i)
                nid[rt * 4 + i] = neuron_id[((size_t)c * NN + row0 + 16 * rt + 4 * g + i) * DD + d0];
        #pragma unroll
        for (int rt = 0; rt < 4; ++rt) {
            f32x4 acc = {0.f, 0.f, 0.f, 0.f};
            #pragma unroll
            for (int k = 0; k < 8; ++k) {
                const s16x8 af = *(const s16x8*)&s_hid[(16 * rt + l15) * 264 + 32 * k + 8 * g];
                acc = MFMA16(af, wf[k], acc);
            }
            #pragma unroll
            for (int i = 0; i < 4; ++i) {
                const int lrow = 16 * rt + 4 * g + i, grow = row0 + lrow;
                const float m = tanh2(acc[i] + mb) + nid[rt * 4 + i];
                out_msg[((size_t)bc * NN + grow) * DD + d0] = m;
                if (tile == 0 && lrow >= 4 && lrow < 8) s_mn[(lrow - 4) * 64 + d0] = m;
            }
        }
    }
    __syncthreads();
    if (tile == 0 && tid < 64)
        out_read[(size_t)b * (NCC * DD) + c * 64 + tid] =
            0.25f * (s_mn[tid] + s_mn[64 + tid] + s_mn[128 + tid] + s_mn[192 + tid]);
}

extern "C" void kernel_launch(void* const* d_in, const int* in_sizes, int n_in,
                              void* d_out, int out_size, void* d_ws, size_t ws_size,
                              hipStream_t stream) {
    (void)in_sizes; (void)n_in; (void)ws_size; (void)out_size;
    const float* x                 = (const float*)d_in[0];
    const float* h                 = (const float*)d_in[1];
    const float* msg               = (const float*)d_in[2];
    const float* W                 = (const float*)d_in[3];
    const float* decay_logit       = (const float*)d_in[4];
    const float* cell_context      = (const float*)d_in[5];
    const float* border_gate_logit = (const float*)d_in[6];
    const float* neuron_id         = (const float*)d_in[7];
    const float* state_w1          = (const float*)d_in[8];
    const float* state_b1          = (const float*)d_in[9];
    const float* state_w2          = (const float*)d_in[10];
    const float* state_b2          = (const float*)d_in[11];
    const float* msg_w1            = (const float*)d_in[12];
    const float* msg_b1            = (const float*)d_in[13];
    const float* msg_w2            = (const float*)d_in[14];
    const float* msg_b2            = (const float*)d_in[15];
    const float* inject_w          = (const float*)d_in[16];
    const float* inject_b          = (const float*)d_in[17];
    const float* mod_w1            = (const float*)d_in[18];
    const float* mod_b1            = (const float*)d_in[19];
    const float* mod_w2            = (const float*)d_in[20];
    const float* mod_b2            = (const float*)d_in[21];
    const int*   cell_to_group     = (const int*)d_in[22];

    float* out_read = (float*)d_out;
    float* out_h    = out_read + (size_t)BB * NCC * DD;
    float* out_msg  = out_h + (size_t)BB * NCC * NN * DD;

    // ws layout (bytes): [0,163840) bf16 weights | [163840,1212416) decay f32
    //                    | [1212416,34766848) recv bf16
    unsigned short* ws16   = (unsigned short*)d_ws;
    unsigned short* sw1b   = ws16;
    unsigned short* sw2b   = ws16 + 32768;
    unsigned short* mw1b   = ws16 + 49152;
    unsigned short* mw2b   = ws16 + 65536;
    float*          ws_dec = (float*)((char*)d_ws + 163840);
    unsigned short* ws_rcv = (unsigned short*)((char*)d_ws + 1212416);

    hipLaunchKernelGGL(wconv, dim3(320), dim3(256), 0, stream,
                       state_w1, state_w2, msg_w1, msg_w2, ws16);

    hipLaunchKernelGGL(mg_recv, dim3(BB * NCC), dim3(512), 0, stream,
                       x, msg, W, decay_logit, cell_context, border_gate_logit,
                       inject_w, inject_b, mod_w1, mod_b1, mod_w2, mod_b2,
                       cell_to_group, ws_rcv, ws_dec);

    hipLaunchKernelGGL(mg_mlp, dim3(BB * NCC * 4), dim3(256), 0, stream,
                       h, neuron_id, state_b1, state_b2, msg_b1, msg_b2,
                       sw1b, sw2b, mw1b, mw2b, ws_rcv, ws_dec,
                       out_read, out_h, out_msg);
}